// Round 2
// baseline (16282.681 us; speedup 1.0000x reference)
//
#include <hip/hip_runtime.h>
#include <stdint.h>

typedef __attribute__((ext_vector_type(8))) short short8;
typedef __attribute__((ext_vector_type(4))) float floatx4;
typedef unsigned short u16;
typedef unsigned int u32;

constexpr int BSZ = 64;     // batch
constexpr int SEQT = 512;   // encoder timesteps
constexpr int FIN = 64;     // input features F
constexpr int HID = 512;    // hidden H
constexpr int NG = 2048;    // 4*H gate rows
constexpr int FUTL = 96;    // decoder steps
constexpr int K0 = FIN + HID;   // 576  (layer-0 concat K)
constexpr int K1 = HID + HID;   // 1024 (layer-1 concat K)
constexpr int K0P = K0 + 8;     // padded LDS row stride for layer-0 W
constexpr int NBLK = 256;
constexpr int NTHR = 256;
constexpr int SLOT_H = BSZ * HID;  // 32768 elems
constexpr int SLOT_X = BSZ * FIN;  // 4096 elems

// ---------------- workspace layout (bytes) ----------------
constexpr size_t S_W0 = (size_t)NG * K0 * 2;
constexpr size_t S_W1 = (size_t)NG * K1 * 2;
constexpr size_t S_FC = (size_t)FIN * HID * 2;
constexpr size_t S_X  = (size_t)SEQT * BSZ * FIN * 2;
constexpr size_t S_DX = (size_t)2 * BSZ * FIN * 2;      // 2-slot ring
constexpr size_t S_HR = (size_t)4 * BSZ * HID * 2;      // 4-slot ring, one component

constexpr size_t OFF_WHI_E0 = 0;
constexpr size_t OFF_WLO_E0 = OFF_WHI_E0 + S_W0;
constexpr size_t OFF_WHI_E1 = OFF_WLO_E0 + S_W0;
constexpr size_t OFF_WLO_E1 = OFF_WHI_E1 + S_W1;
constexpr size_t OFF_WHI_D0 = OFF_WLO_E1 + S_W1;
constexpr size_t OFF_WLO_D0 = OFF_WHI_D0 + S_W0;
constexpr size_t OFF_WHI_D1 = OFF_WLO_D0 + S_W0;
constexpr size_t OFF_WLO_D1 = OFF_WHI_D1 + S_W1;
constexpr size_t OFF_FCHI  = OFF_WLO_D1 + S_W1;
constexpr size_t OFF_FCLO  = OFF_FCHI + S_FC;
constexpr size_t OFF_XHI   = OFF_FCLO + S_FC;
constexpr size_t OFF_XLO   = OFF_XHI + S_X;
constexpr size_t OFF_DXHI  = OFF_XLO + S_X;    // memset region starts here
constexpr size_t OFF_DXLO  = OFF_DXHI + S_DX;
constexpr size_t OFF_H0HI  = OFF_DXLO + S_DX;
constexpr size_t OFF_H0LO  = OFF_H0HI + S_HR;
constexpr size_t OFF_H1HI  = OFF_H0LO + S_HR;
constexpr size_t OFF_H1LO  = OFF_H1HI + S_HR;
constexpr size_t OFF_CNT   = OFF_H1LO + S_HR;
constexpr size_t OFF_END   = OFF_CNT + 4096;
constexpr size_t MEMSET_BYTES = OFF_END - OFF_DXHI;

// ---------------- bf16 split helpers ----------------
__device__ __forceinline__ u16 f2bf(float f) {
  u32 u = __float_as_uint(f);
  u += 0x7FFFu + ((u >> 16) & 1u);   // RNE
  return (u16)(u >> 16);
}
__device__ __forceinline__ float bf2f(u16 h) {
  return __uint_as_float(((u32)h) << 16);
}

__device__ __forceinline__ float sigf(float x) { return 1.f / (1.f + __expf(-x)); }
__device__ __forceinline__ float tanh_f(float x) {
  float xx = fminf(20.f, fmaxf(-20.f, x));
  float e = __expf(-2.f * xx);
  return (1.f - e) / (1.f + e);
}

__device__ __forceinline__ floatx4 mfma3(short8 ah, short8 al, short8 bh, short8 bl, floatx4 acc) {
  acc = __builtin_amdgcn_mfma_f32_16x16x32_bf16(ah, bh, acc, 0, 0, 0);
  acc = __builtin_amdgcn_mfma_f32_16x16x32_bf16(ah, bl, acc, 0, 0, 0);
  acc = __builtin_amdgcn_mfma_f32_16x16x32_bf16(al, bh, acc, 0, 0, 0);
  return acc;
}

// write-through store (sc0 sc1): data lands at the coherent point (IF$) immediately,
// no buffer_wbl2 fence needed on the release side.
__device__ __forceinline__ void st_sc_u16(u16* p, u16 v) {
  asm volatile("global_store_short %0, %1, off sc0 sc1" :: "v"(p), "v"((u32)v) : "memory");
}
#define WAITVM0() asm volatile("s_waitcnt vmcnt(0)" ::: "memory")

// ---------------- prep kernels ----------------
__global__ void k_split_pair(const float* __restrict__ Wih, const float* __restrict__ Whh,
                             int ins, int K, u16* __restrict__ hi, u16* __restrict__ lo) {
  int n = NG * K;
  for (int idx = blockIdx.x * blockDim.x + threadIdx.x; idx < n; idx += gridDim.x * blockDim.x) {
    int row = idx / K;
    int k = idx - row * K;
    float v = (k < ins) ? Wih[row * ins + k] : Whh[row * HID + (k - ins)];
    u16 h = f2bf(v);
    hi[idx] = h;
    lo[idx] = f2bf(v - bf2f(h));
  }
}

__global__ void k_split_flat(const float* __restrict__ src, u16* __restrict__ hi,
                             u16* __restrict__ lo, int n) {
  for (int idx = blockIdx.x * blockDim.x + threadIdx.x; idx < n; idx += gridDim.x * blockDim.x) {
    float v = src[idx];
    u16 h = f2bf(v);
    hi[idx] = h;
    lo[idx] = f2bf(v - bf2f(h));
  }
}

__global__ void k_split_x(const float* __restrict__ x, u16* __restrict__ xh, u16* __restrict__ xl,
                          u16* __restrict__ dxh, u16* __restrict__ dxl) {
  int n = BSZ * SEQT * FIN;
  for (int idx = blockIdx.x * blockDim.x + threadIdx.x; idx < n; idx += gridDim.x * blockDim.x) {
    int t = idx / (BSZ * FIN);
    int rem = idx - t * (BSZ * FIN);
    int b = rem >> 6;
    int f = rem & 63;
    float v = x[(b * SEQT + t) * FIN + f];
    u16 h = f2bf(v);
    u16 l = f2bf(v - bf2f(h));
    xh[idx] = h;
    xl[idx] = l;
    if (t == SEQT - 1) { dxh[(b << 6) + f] = h; dxl[(b << 6) + f] = l; }
  }
}

// ---------------- params ----------------
struct Params {
  const u16 *we0h, *we0l, *we1h, *we1l;
  const u16 *wd0h, *wd0l, *wd1h, *wd1l;
  const u16 *fch, *fcl;
  const u16 *xhi, *xlo;
  u16 *h0h, *h0l, *h1h, *h1l, *dxh, *dxl;
  const float *beih0, *behh0, *beih1, *behh1;
  const float *bdih0, *bdhh0, *bdih1, *bdhh1;
  const float *fcb;
  float *out;
  u32 *cnt;
};

// ---------------- sync primitives ----------------
__device__ __forceinline__ void spin_until(u32* ctr, u32 tgt) {
  int sp = 0;
  while (__hip_atomic_load(ctr, __ATOMIC_RELAXED, __HIP_MEMORY_SCOPE_AGENT) < tgt) {
    if (sp < 16) __builtin_amdgcn_s_sleep(2);
    else         __builtin_amdgcn_s_sleep(32);
    ++sp;
  }
}

// after a gate/barrier: all waves invalidate stale L1/L2 (per-wave buffer_inv), then
// normal cached loads pull fresh lines from IF$ (local L2 absorbs the 32x broadcast).
__device__ __forceinline__ void gate_fence() {
  __syncthreads();
  __builtin_amdgcn_fence(__ATOMIC_ACQUIRE, "agent");
}

// 128-block group barrier: 8 leaves x 16 blocks, monotonic counters, no data fences
// (release is handled by sc0/sc1 write-through stores + per-wave vmcnt(0)).
__device__ __forceinline__ void group_barrier(u32* root, u32* leaves, int lidx, u32 gen) {
  WAITVM0();          // every wave drains its own sc stores
  __syncthreads();
  if (threadIdx.x == 0) {
    u32* leaf = leaves + ((lidx & 7) << 4);  // 64B-spaced
    u32 a = __hip_atomic_fetch_add(leaf, 1u, __ATOMIC_RELAXED, __HIP_MEMORY_SCOPE_AGENT) + 1u;
    if (a == gen * 16u)
      __hip_atomic_fetch_add(root, 1u, __ATOMIC_RELAXED, __HIP_MEMORY_SCOPE_AGENT);
    spin_until(root, gen * 8u);
  }
  gate_fence();
}

// ---------------- W -> LDS (persistent) ----------------
template <bool IS_L1>
__device__ void load_w_lds(const u16* __restrict__ gh, const u16* __restrict__ gl,
                           u16* wh, u16* wl, int hc) {
  constexpr int K = IS_L1 ? K1 : K0;
  for (int i = threadIdx.x; i < 16 * K; i += NTHR) {
    int rr, k;
    if (IS_L1) { rr = i >> 10; k = i & 1023; }
    else       { rr = i / K0;  k = i - rr * K0; }
    int gc = ((rr >> 2) * HID) + hc + (rr & 3);   // row r -> gate q=r>>2, col j=r&3
    int dst = IS_L1 ? ((rr << 10) + ((((k >> 3) ^ rr)) << 3) + (k & 7))
                    : (rr * K0P + k);
    wh[dst] = gh[(size_t)gc * K + k];
    wl[dst] = gl[(size_t)gc * K + k];
  }
  __syncthreads();
}

// ---------------- one LSTM layer step for this block's 4 h-columns ----------------
template <bool IS_L1>
__device__ void layer_step(const u16* __restrict__ s0h, const u16* __restrict__ s0l,
                           const u16* __restrict__ s1h, const u16* __restrict__ s1l,
                           const u16* __restrict__ wh, const u16* __restrict__ wl,
                           floatx4 bs, float& creg,
                           u16* __restrict__ ohh, u16* __restrict__ ohl, int hc) {
  constexpr int LEN0 = IS_L1 ? HID : FIN;
  const int tid = threadIdx.x, lane = tid & 63, w = tid >> 6;
  const int quad = lane >> 4, r = lane & 15;
  const int m = (w << 4) + r;       // A row for this lane's fragment
  const int qo = quad << 3;
  floatx4 acc = {0.f, 0.f, 0.f, 0.f};

#pragma unroll 4
  for (int kk = 0; kk < LEN0; kk += 32) {
    const int ao = m * LEN0 + kk + qo;
    short8 ah = *(const short8*)(s0h + ao);
    short8 al = *(const short8*)(s0l + ao);
    int woff;
    if (IS_L1) { int c = (kk >> 3) + quad; woff = (r << 10) + ((c ^ r) << 3); }
    else       { woff = r * K0P + kk + qo; }
    short8 bh = *(const short8*)(wh + woff);
    short8 bl = *(const short8*)(wl + woff);
    acc = mfma3(ah, al, bh, bl, acc);
  }
#pragma unroll 4
  for (int kk = 0; kk < HID; kk += 32) {
    const int ao = m * HID + kk + qo;
    short8 ah = *(const short8*)(s1h + ao);
    short8 al = *(const short8*)(s1l + ao);
    const int kg = kk + LEN0;
    int woff;
    if (IS_L1) { int c = (kg >> 3) + quad; woff = (r << 10) + ((c ^ r) << 3); }
    else       { woff = r * K0P + kg + qo; }
    short8 bh = *(const short8*)(wh + woff);
    short8 bl = *(const short8*)(wl + woff);
    acc = mfma3(ah, al, bh, bl, acc);
  }

  // Epilogue: C[row=quad*4+i][col=r] -> each lane owns one (b, j) with its 4 gates.
  const int j = lane & 3;
  const int rw = lane >> 2;
  const int b = (w << 4) + rw;
  const int isel = rw & 3;
  const int slb = lane & 48;
  float gate[4];
#pragma unroll
  for (int q = 0; q < 4; ++q) {
    const int sl = slb + (q << 2) + j;
    float t0 = __shfl(acc[0], sl, 64);
    float t1 = __shfl(acc[1], sl, 64);
    float t2 = __shfl(acc[2], sl, 64);
    float t3 = __shfl(acc[3], sl, 64);
    gate[q] = (isel == 0) ? t0 : (isel == 1) ? t1 : (isel == 2) ? t2 : t3;
  }

  const int ch = hc + j;
  const int idx = b * HID + ch;
  float iv = gate[0] + bs[0];
  float fv = gate[1] + bs[1];
  float gv = gate[2] + bs[2];
  float ov = gate[3] + bs[3];
  float cn = fmaf(sigf(fv), creg, sigf(iv) * tanh_f(gv));
  float hn = sigf(ov) * tanh_f(cn);
  creg = cn;                        // cell state lives in a register forever
  u16 hh = f2bf(hn);
  u16 hl = f2bf(hn - bf2f(hh));
  st_sc_u16(ohh + idx, hh);         // write-through: visible at IF$ after vmcnt(0)
  st_sc_u16(ohl + idx, hl);
}

// ---------------- decoder fc (blocks 0..3): out = dh1 @ fcW^T + fcb ----------------
__device__ void fc_step(int t, int blk,
                        const u16* __restrict__ ah, const u16* __restrict__ al,
                        const u16* __restrict__ fh, const u16* __restrict__ fl,
                        const float* __restrict__ fcb, float* __restrict__ out,
                        u16* __restrict__ dxh, u16* __restrict__ dxl) {
  const int tid = threadIdx.x, lane = tid & 63, w = tid >> 6;
  const int quad = lane >> 4, r = lane & 15;
  const int m = (w << 4) + r;
  const int qo = quad << 3;
  const int col = (blk << 4) + r;
  floatx4 acc = {0.f, 0.f, 0.f, 0.f};
#pragma unroll 4
  for (int kk = 0; kk < HID; kk += 32) {
    short8 a1 = *(const short8*)(ah + m * HID + kk + qo);
    short8 a2 = *(const short8*)(al + m * HID + kk + qo);
    short8 b1 = *(const short8*)(fh + col * HID + kk + qo);
    short8 b2 = *(const short8*)(fl + col * HID + kk + qo);
    acc = mfma3(a1, a2, b1, b2, acc);
  }
  float bias = fcb[col];
#pragma unroll
  for (int i = 0; i < 4; ++i) {
    int b = (w << 4) + (quad << 2) + i;
    float v = acc[i] + bias;
    out[(b * FUTL + t) * FIN + col] = v;   // normal store, flushed at kernel end
    u16 hv = f2bf(v);
    st_sc_u16(dxh + b * FIN + col, hv);
    st_sc_u16(dxl + b * FIN + col, f2bf(v - bf2f(hv)));
  }
}

// ---------------- the persistent kernel ----------------
// Two decoupled 128-block groups: group0 = layer0(+fc), group1 = layer1.
// h rings are 4 deep; cross-group ordering via watching the other group's root counter.
__global__ __launch_bounds__(NTHR, 1) void lstm_coop(Params p) {
  __shared__ u16 wsmem[32768];              // 64 KB
  u16* wh = wsmem;
  u16* wl = wsmem + 16 * 1024;
  const int blk = blockIdx.x;
  const int grp = blk >> 7;
  const int lidx = blk & 127;
  const int hc = lidx << 2;

  u32* root0  = p.cnt;                       // group0 root (8 leaves -> +8/gen)
  u32* leaves0 = p.cnt + 16;
  u32* root1  = p.cnt + 256;
  u32* leaves1 = p.cnt + 272;
  u32* fcflag = p.cnt + 512;                 // +4 per fc step

  floatx4 bse, bsd;                          // per-thread gate bias sums, enc & dec
  {
    int ch = hc + (threadIdx.x & 3);
    const float* bi  = grp ? p.beih1 : p.beih0;
    const float* bh2 = grp ? p.behh1 : p.behh0;
    const float* di  = grp ? p.bdih1 : p.bdih0;
    const float* dh2 = grp ? p.bdhh1 : p.bdhh0;
#pragma unroll
    for (int q = 0; q < 4; ++q) {
      bse[q] = bi[q * HID + ch] + bh2[q * HID + ch];
      bsd[q] = di[q * HID + ch] + dh2[q * HID + ch];
    }
  }
  float creg = 0.f;                          // encoder-final c feeds decoder directly

  if (!grp) {
    // ======== group0: encoder layer0 ========
    load_w_lds<false>(p.we0h, p.we0l, wh, wl, hc);
    for (int s = 0; s < SEQT; ++s) {
      if (s >= 4) {                          // ring overwrite gate: group1 done step s-4
        if (threadIdx.x == 0) spin_until(root1, 8u * (u32)(s - 3));
        gate_fence();
      }
      layer_step<false>(p.xhi + (size_t)s * SLOT_X, p.xlo + (size_t)s * SLOT_X,
                        p.h0h + ((s + 3) & 3) * SLOT_H, p.h0l + ((s + 3) & 3) * SLOT_H,
                        wh, wl, bse, creg,
                        p.h0h + (s & 3) * SLOT_H, p.h0l + (s & 3) * SLOT_H, hc);
      group_barrier(root0, leaves0, lidx, (u32)(s + 1));
    }
    // ======== group0: decoder layer0 (+fc on blocks 0..3) ========
    load_w_lds<false>(p.wd0h, p.wd0l, wh, wl, hc);
    for (int t = 0; t < FUTL; ++t) {
      if (threadIdx.x == 0) {
        spin_until(fcflag, 4u * (u32)t);                 // dx(t) ready
        spin_until(root1, 8u * (u32)(509 + t));          // ring overwrite gate
      }
      gate_fence();
      layer_step<false>(p.dxh + (t & 1) * SLOT_X, p.dxl + (t & 1) * SLOT_X,
                        p.h0h + ((511 + t) & 3) * SLOT_H, p.h0l + ((511 + t) & 3) * SLOT_H,
                        wh, wl, bsd, creg,
                        p.h0h + ((512 + t) & 3) * SLOT_H, p.h0l + ((512 + t) & 3) * SLOT_H, hc);
      group_barrier(root0, leaves0, lidx, (u32)(513 + t));
      if (blk < 4) {
        if (threadIdx.x == 0) spin_until(root1, 8u * (u32)(513 + t));  // h1-dec(t) ready
        gate_fence();
        fc_step(t, blk, p.h1h + ((512 + t) & 3) * SLOT_H, p.h1l + ((512 + t) & 3) * SLOT_H,
                p.fch, p.fcl, p.fcb, p.out,
                p.dxh + ((t + 1) & 1) * SLOT_X, p.dxl + ((t + 1) & 1) * SLOT_X);
        WAITVM0();
        __syncthreads();
        if (threadIdx.x == 0)
          __hip_atomic_fetch_add(fcflag, 1u, __ATOMIC_RELAXED, __HIP_MEMORY_SCOPE_AGENT);
      }
    }
  } else {
    // ======== group1: encoder layer1 ========
    load_w_lds<true>(p.we1h, p.we1l, wh, wl, hc);
    for (int t = 0; t < SEQT; ++t) {
      if (threadIdx.x == 0) spin_until(root0, 8u * (u32)(t + 1));   // h0(t) ready
      gate_fence();
      layer_step<true>(p.h0h + (t & 3) * SLOT_H, p.h0l + (t & 3) * SLOT_H,
                       p.h1h + ((t + 3) & 3) * SLOT_H, p.h1l + ((t + 3) & 3) * SLOT_H,
                       wh, wl, bse, creg,
                       p.h1h + (t & 3) * SLOT_H, p.h1l + (t & 3) * SLOT_H, hc);
      group_barrier(root1, leaves1, lidx, (u32)(t + 1));
    }
    // ======== group1: decoder layer1 ========
    load_w_lds<true>(p.wd1h, p.wd1l, wh, wl, hc);
    for (int t = 0; t < FUTL; ++t) {
      if (threadIdx.x == 0) {
        spin_until(root0, 8u * (u32)(513 + t));          // h0-dec(t) ready
        if (t >= 4) spin_until(fcflag, 4u * (u32)(t - 3));  // ring overwrite gate (fc reads)
      }
      gate_fence();
      layer_step<true>(p.h0h + ((512 + t) & 3) * SLOT_H, p.h0l + ((512 + t) & 3) * SLOT_H,
                       p.h1h + ((511 + t) & 3) * SLOT_H, p.h1l + ((511 + t) & 3) * SLOT_H,
                       wh, wl, bsd, creg,
                       p.h1h + ((512 + t) & 3) * SLOT_H, p.h1l + ((512 + t) & 3) * SLOT_H, hc);
      group_barrier(root1, leaves1, lidx, (u32)(513 + t));
    }
  }
}

// ---------------- launch ----------------
extern "C" void kernel_launch(void* const* d_in, const int* in_sizes, int n_in,
                              void* d_out, int out_size, void* d_ws, size_t ws_size,
                              hipStream_t stream) {
  (void)in_sizes; (void)n_in; (void)out_size; (void)ws_size;
  const float* in_seq = (const float*)d_in[0];
  const float* eWih0 = (const float*)d_in[1];
  const float* eWhh0 = (const float*)d_in[2];
  const float* ebih0 = (const float*)d_in[3];
  const float* ebhh0 = (const float*)d_in[4];
  const float* eWih1 = (const float*)d_in[5];
  const float* eWhh1 = (const float*)d_in[6];
  const float* ebih1 = (const float*)d_in[7];
  const float* ebhh1 = (const float*)d_in[8];
  const float* dWih0 = (const float*)d_in[9];
  const float* dWhh0 = (const float*)d_in[10];
  const float* dbih0 = (const float*)d_in[11];
  const float* dbhh0 = (const float*)d_in[12];
  const float* dWih1 = (const float*)d_in[13];
  const float* dWhh1 = (const float*)d_in[14];
  const float* dbih1 = (const float*)d_in[15];
  const float* dbhh1 = (const float*)d_in[16];
  const float* fcW  = (const float*)d_in[17];
  const float* fcb  = (const float*)d_in[18];

  char* ws = (char*)d_ws;
  u16* we0h = (u16*)(ws + OFF_WHI_E0); u16* we0l = (u16*)(ws + OFF_WLO_E0);
  u16* we1h = (u16*)(ws + OFF_WHI_E1); u16* we1l = (u16*)(ws + OFF_WLO_E1);
  u16* wd0h = (u16*)(ws + OFF_WHI_D0); u16* wd0l = (u16*)(ws + OFF_WLO_D0);
  u16* wd1h = (u16*)(ws + OFF_WHI_D1); u16* wd1l = (u16*)(ws + OFF_WLO_D1);
  u16* fch  = (u16*)(ws + OFF_FCHI);   u16* fcl  = (u16*)(ws + OFF_FCLO);
  u16* xhi  = (u16*)(ws + OFF_XHI);    u16* xlo  = (u16*)(ws + OFF_XLO);
  u16* dxh  = (u16*)(ws + OFF_DXHI);   u16* dxl  = (u16*)(ws + OFF_DXLO);
  u16* h0h  = (u16*)(ws + OFF_H0HI);   u16* h0l  = (u16*)(ws + OFF_H0LO);
  u16* h1h  = (u16*)(ws + OFF_H1HI);   u16* h1l  = (u16*)(ws + OFF_H1LO);
  u32* cnt  = (u32*)(ws + OFF_CNT);

  // zero rings + dx + counters (ws is poisoned 0xAA before every call)
  hipMemsetAsync(ws + OFF_DXHI, 0, MEMSET_BYTES, stream);

  k_split_pair<<<512, 256, 0, stream>>>(eWih0, eWhh0, FIN, K0, we0h, we0l);
  k_split_pair<<<512, 256, 0, stream>>>(eWih1, eWhh1, HID, K1, we1h, we1l);
  k_split_pair<<<512, 256, 0, stream>>>(dWih0, dWhh0, FIN, K0, wd0h, wd0l);
  k_split_pair<<<512, 256, 0, stream>>>(dWih1, dWhh1, HID, K1, wd1h, wd1l);
  k_split_flat<<<128, 256, 0, stream>>>(fcW, fch, fcl, FIN * HID);
  k_split_x<<<1024, 256, 0, stream>>>(in_seq, xhi, xlo, dxh, dxl);

  Params p;
  p.we0h = we0h; p.we0l = we0l; p.we1h = we1h; p.we1l = we1l;
  p.wd0h = wd0h; p.wd0l = wd0l; p.wd1h = wd1h; p.wd1l = wd1l;
  p.fch = fch; p.fcl = fcl;
  p.xhi = xhi; p.xlo = xlo;
  p.h0h = h0h; p.h0l = h0l; p.h1h = h1h; p.h1l = h1l;
  p.dxh = dxh; p.dxl = dxl;
  p.beih0 = ebih0; p.behh0 = ebhh0; p.beih1 = ebih1; p.behh1 = ebhh1;
  p.bdih0 = dbih0; p.bdhh0 = dbhh0; p.bdih1 = dbih1; p.bdhh1 = dbhh1;
  p.fcb = fcb;
  p.out = (float*)d_out;
  p.cnt = cnt;

  lstm_coop<<<dim3(NBLK), dim3(NTHR), 0, stream>>>(p);
}

// Round 3
// 8930.289 us; speedup vs baseline: 1.8233x; 1.8233x over previous
//
#include <hip/hip_runtime.h>
#include <stdint.h>

typedef __attribute__((ext_vector_type(8))) short short8;
typedef __attribute__((ext_vector_type(4))) float floatx4;
typedef unsigned short u16;
typedef unsigned int u32;

constexpr int BSZ = 64;     // batch
constexpr int SEQT = 512;   // encoder timesteps
constexpr int FIN = 64;     // input features F
constexpr int HID = 512;    // hidden H
constexpr int NG = 2048;    // 4*H gate rows
constexpr int FUTL = 96;    // decoder steps
constexpr int K0 = FIN + HID;   // 576
constexpr int K1 = HID + HID;   // 1024
constexpr int K0P = K0 + 8;     // padded LDS row stride for layer-0 W
constexpr int NBLK = 256;
constexpr int NTHR = 256;

// packed activation slabs: one slab = 4 cols x 64 batch x u32(hi|lo<<16) = 1KB
constexpr int SLOT_HP = 128 * 256;  // u32 per h slot (128 slabs)
constexpr int SLOT_XP = 16 * 256;   // u32 per x/dx slot (16 slabs)

// ---------------- workspace layout (bytes) ----------------
constexpr size_t S_W0 = (size_t)NG * K0 * 2;
constexpr size_t S_W1 = (size_t)NG * K1 * 2;
constexpr size_t S_FC = (size_t)FIN * HID * 2;

constexpr size_t OFF_WHI_E0 = 0;
constexpr size_t OFF_WLO_E0 = OFF_WHI_E0 + S_W0;
constexpr size_t OFF_WHI_E1 = OFF_WLO_E0 + S_W0;
constexpr size_t OFF_WLO_E1 = OFF_WHI_E1 + S_W1;
constexpr size_t OFF_WHI_D0 = OFF_WLO_E1 + S_W1;
constexpr size_t OFF_WLO_D0 = OFF_WHI_D0 + S_W0;
constexpr size_t OFF_WHI_D1 = OFF_WLO_D0 + S_W0;
constexpr size_t OFF_WLO_D1 = OFF_WHI_D1 + S_W1;
constexpr size_t OFF_FCHI  = OFF_WLO_D1 + S_W1;
constexpr size_t OFF_FCLO  = OFF_FCHI + S_FC;
constexpr size_t OFF_XP    = OFF_FCLO + S_FC;                       // 512*4096 u32
constexpr size_t OFF_H0P   = OFF_XP + (size_t)SEQT * SLOT_XP * 4;   // memset from here
constexpr size_t OFF_H1P   = OFF_H0P + (size_t)4 * SLOT_HP * 4;
constexpr size_t OFF_DXP   = OFF_H1P + (size_t)4 * SLOT_HP * 4;
constexpr size_t OFF_CNT   = OFF_DXP + (size_t)2 * SLOT_XP * 4;
constexpr size_t OFF_END   = OFF_CNT + 32768;
constexpr size_t MEMSET_BYTES = OFF_END - OFF_H0P;

// cnt layout (u32 index): fcflag @0; leaves0 @16 (16 cells x16); leaves1 @512;
// go0 @1024 (128 cells x16); go1 @3072.
#define FCFLAG(c)  ((c) + 0)
#define LEAVES0(c) ((c) + 16)
#define LEAVES1(c) ((c) + 512)
#define GO0(c)     ((c) + 1024)
#define GO1(c)     ((c) + 3072)

// ---------------- bf16 helpers ----------------
__device__ __forceinline__ u16 f2bf(float f) {
  u32 u = __float_as_uint(f);
  u += 0x7FFFu + ((u >> 16) & 1u);   // RNE
  return (u16)(u >> 16);
}
__device__ __forceinline__ float bf2f(u16 h) { return __uint_as_float(((u32)h) << 16); }
__device__ __forceinline__ u32 packsplit(float v) {
  u16 h = f2bf(v);
  u16 l = f2bf(v - bf2f(h));
  return (u32)h | ((u32)l << 16);
}

__device__ __forceinline__ float sigf(float x) { return 1.f / (1.f + __expf(-x)); }
__device__ __forceinline__ float tanh_f(float x) {
  float xx = fminf(20.f, fmaxf(-20.f, x));
  float e = __expf(-2.f * xx);
  return (1.f - e) / (1.f + e);
}

__device__ __forceinline__ floatx4 mfma3(short8 ah, short8 al, short8 bh, short8 bl, floatx4 acc) {
  acc = __builtin_amdgcn_mfma_f32_16x16x32_bf16(ah, bh, acc, 0, 0, 0);
  acc = __builtin_amdgcn_mfma_f32_16x16x32_bf16(ah, bl, acc, 0, 0, 0);
  acc = __builtin_amdgcn_mfma_f32_16x16x32_bf16(al, bh, acc, 0, 0, 0);
  return acc;
}

// write-through store: lands at the coherent point (IF$); no release fence needed.
__device__ __forceinline__ void st_sc_u32(u32* p, u32 v) {
  asm volatile("global_store_dword %0, %1, off sc0 sc1" :: "v"(p), "v"(v) : "memory");
}
#define WAITVM0() asm volatile("s_waitcnt vmcnt(0)" ::: "memory")

#define ALD(p) __hip_atomic_load((p), __ATOMIC_RELAXED, __HIP_MEMORY_SCOPE_AGENT)
#define AST(p, v) __hip_atomic_store((p), (v), __ATOMIC_RELAXED, __HIP_MEMORY_SCOPE_AGENT)
#define AADD(p, v) __hip_atomic_fetch_add((p), (v), __ATOMIC_RELAXED, __HIP_MEMORY_SCOPE_AGENT)

// packed A-fragment load: 8 cols (2 slabs) for batch row m -> hi/lo short8
__device__ __forceinline__ void ld_frag(const u32* p, short8& ah, short8& al) {
  uint4 a = *(const uint4*)p;
  uint4 b = *(const uint4*)(p + 256);
  union { u32 u[4]; short8 s; } H, L;
  H.u[0] = __builtin_amdgcn_perm(a.y, a.x, 0x05040100u);
  L.u[0] = __builtin_amdgcn_perm(a.y, a.x, 0x07060302u);
  H.u[1] = __builtin_amdgcn_perm(a.w, a.z, 0x05040100u);
  L.u[1] = __builtin_amdgcn_perm(a.w, a.z, 0x07060302u);
  H.u[2] = __builtin_amdgcn_perm(b.y, b.x, 0x05040100u);
  L.u[2] = __builtin_amdgcn_perm(b.y, b.x, 0x07060302u);
  H.u[3] = __builtin_amdgcn_perm(b.w, b.z, 0x05040100u);
  L.u[3] = __builtin_amdgcn_perm(b.w, b.z, 0x07060302u);
  ah = H.s; al = L.s;
}

// ---------------- prep kernels ----------------
__global__ void k_split_pair(const float* __restrict__ Wih, const float* __restrict__ Whh,
                             int ins, int K, u16* __restrict__ hi, u16* __restrict__ lo) {
  int n = NG * K;
  for (int idx = blockIdx.x * blockDim.x + threadIdx.x; idx < n; idx += gridDim.x * blockDim.x) {
    int row = idx / K;
    int k = idx - row * K;
    float v = (k < ins) ? Wih[row * ins + k] : Whh[row * HID + (k - ins)];
    u16 h = f2bf(v);
    hi[idx] = h;
    lo[idx] = f2bf(v - bf2f(h));
  }
}

__global__ void k_split_flat(const float* __restrict__ src, u16* __restrict__ hi,
                             u16* __restrict__ lo, int n) {
  for (int idx = blockIdx.x * blockDim.x + threadIdx.x; idx < n; idx += gridDim.x * blockDim.x) {
    float v = src[idx];
    u16 h = f2bf(v);
    hi[idx] = h;
    lo[idx] = f2bf(v - bf2f(h));
  }
}

// input_seq [B][T][F] -> packed slabs xp[t][kb][m][j]; also dxp slot 0 from t=T-1
__global__ void k_pack_x(const float* __restrict__ x, u32* __restrict__ xp, u32* __restrict__ dxp) {
  int n = BSZ * SEQT * FIN;
  for (int idx = blockIdx.x * blockDim.x + threadIdx.x; idx < n; idx += gridDim.x * blockDim.x) {
    int t = idx / (BSZ * FIN);
    int rem = idx - t * (BSZ * FIN);
    int b = rem >> 6;
    int f = rem & 63;
    u32 pk = packsplit(x[(b * SEQT + t) * FIN + f]);
    int off = ((f >> 2) * 64 + b) * 4 + (f & 3);
    xp[t * SLOT_XP + off] = pk;
    if (t == SEQT - 1) dxp[off] = pk;
  }
}

// ---------------- params ----------------
struct Params {
  const u16 *we0h, *we0l, *we1h, *we1l;
  const u16 *wd0h, *wd0l, *wd1h, *wd1l;
  const u16 *fch, *fcl;
  const u32 *xp;
  u32 *h0p, *h1p, *dxp;
  const float *beih0, *behh0, *beih1, *behh1;
  const float *bdih0, *bdhh0, *bdih1, *bdhh1;
  const float *fcb;
  float *out;
  u32 *cnt;
};

// ---------------- sync ----------------
// Master-side wait: wave0 sweeps 16-cell arrival arrays (64B-spaced) + optional flag.
__device__ void master_wait(u32* ownL, u32 ownT, u32* forL, u32 forT, u32* fcf, u32 fcT) {
  if (threadIdx.x < 64) {
    int l = threadIdx.x;
    for (;;) {
      bool ok = true;
      if (l < 16)              ok = ALD(ownL + l * 16) >= ownT;
      else if (l < 32 && forL) ok = ALD(forL + (l - 16) * 16) >= forT;
      else if (l == 32 && fcf) ok = ALD(fcf) >= fcT;
      if (__all(ok)) break;
      __builtin_amdgcn_s_sleep(2);
    }
  }
  __syncthreads();
}

// Worker: poll OWN go cell only (1 poller per line).
__device__ __forceinline__ void worker_wait(u32* cell, u32 tok) {
  if (threadIdx.x == 0) {
    while (ALD(cell) < tok) __builtin_amdgcn_s_sleep(2);
  }
  __syncthreads();
}

__device__ __forceinline__ void fence_acq() {
  __builtin_amdgcn_fence(__ATOMIC_ACQUIRE, "agent");
}

// Arrival: drain own sc stores (per wave), then one add to this block's leaf cell.
__device__ __forceinline__ void arrive(u32* leafcell) {
  WAITVM0();
  __syncthreads();
  if (threadIdx.x == 0) AADD(leafcell, 1u);
}

// ---------------- W -> LDS (persistent; same scheme as verified R2) ----------------
template <bool IS_L1>
__device__ void load_w_lds(const u16* __restrict__ gh, const u16* __restrict__ gl,
                           u16* wh, u16* wl, int hc) {
  constexpr int K = IS_L1 ? K1 : K0;
  for (int i = threadIdx.x; i < 16 * K; i += NTHR) {
    int rr, k;
    if (IS_L1) { rr = i >> 10; k = i & 1023; }
    else       { rr = i / K0;  k = i - rr * K0; }
    int gc = ((rr >> 2) * HID) + hc + (rr & 3);   // row r -> gate q=r>>2, col j=r&3
    int dst = IS_L1 ? ((rr << 10) + ((((k >> 3) ^ rr)) << 3) + (k & 7))
                    : (rr * K0P + k);
    wh[dst] = gh[(size_t)gc * K + k];
    wl[dst] = gl[(size_t)gc * K + k];
  }
  __syncthreads();
}

// ---------------- one LSTM layer step (block's 4 h-cols) ----------------
template <bool IS_L1>
__device__ void layer_step(const u32* __restrict__ s0p, const u32* __restrict__ s1p,
                           const u16* __restrict__ wh, const u16* __restrict__ wl,
                           floatx4 bs, float& creg, u32* __restrict__ oslab) {
  constexpr int LEN0 = IS_L1 ? HID : FIN;
  const int tid = threadIdx.x, lane = tid & 63, w = tid >> 6;
  const int quad = lane >> 4, r = lane & 15;
  const int m = (w << 4) + r;
  const int qo = quad << 3;
  const int mo = m << 2;
  floatx4 acc = {0.f, 0.f, 0.f, 0.f};

#pragma unroll 2
  for (int kk = 0; kk < LEN0; kk += 32) {
    short8 ah, al;
    ld_frag(s0p + (((kk + qo) >> 2) << 8) + mo, ah, al);
    int woff;
    if (IS_L1) { int c = (kk >> 3) + quad; woff = (r << 10) + ((c ^ r) << 3); }
    else       { woff = r * K0P + kk + qo; }
    short8 bh = *(const short8*)(wh + woff);
    short8 bl = *(const short8*)(wl + woff);
    acc = mfma3(ah, al, bh, bl, acc);
  }
#pragma unroll 4
  for (int kk = 0; kk < HID; kk += 32) {
    short8 ah, al;
    ld_frag(s1p + (((kk + qo) >> 2) << 8) + mo, ah, al);
    const int kg = kk + LEN0;
    int woff;
    if (IS_L1) { int c = (kg >> 3) + quad; woff = (r << 10) + ((c ^ r) << 3); }
    else       { woff = r * K0P + kg + qo; }
    short8 bh = *(const short8*)(wh + woff);
    short8 bl = *(const short8*)(wl + woff);
    acc = mfma3(ah, al, bh, bl, acc);
  }

  // Epilogue: C[row=quad*4+i][col=r]; redistribute so each thread owns one (b, j).
  const int j = lane & 3;
  const int rw = lane >> 2;
  const int isel = rw & 3;
  const int slb = lane & 48;
  float gate[4];
#pragma unroll
  for (int q = 0; q < 4; ++q) {
    const int sl = slb + (q << 2) + j;
    float t0 = __shfl(acc[0], sl, 64);
    float t1 = __shfl(acc[1], sl, 64);
    float t2 = __shfl(acc[2], sl, 64);
    float t3 = __shfl(acc[3], sl, 64);
    gate[q] = (isel == 0) ? t0 : (isel == 1) ? t1 : (isel == 2) ? t2 : t3;
  }

  float iv = gate[0] + bs[0];
  float fv = gate[1] + bs[1];
  float gv = gate[2] + bs[2];
  float ov = gate[3] + bs[3];
  float cn = fmaf(sigf(fv), creg, sigf(iv) * tanh_f(gv));
  float hn = sigf(ov) * tanh_f(cn);
  creg = cn;
  // slab offset for (b = w*16 + rw, j) is exactly tid -> wave-contiguous 256B store
  st_sc_u32(oslab + tid, packsplit(hn));
}

// ---------------- decoder fc (blocks 0..3): out = dh1 @ fcW^T + fcb ----------------
__device__ void fc_step(int t, int blk, const u32* __restrict__ h1slot,
                        const u16* __restrict__ fh, const u16* __restrict__ fl,
                        const float* __restrict__ fcb, float* __restrict__ out,
                        u32* __restrict__ dxslot) {
  const int tid = threadIdx.x, lane = tid & 63, w = tid >> 6;
  const int quad = lane >> 4, r = lane & 15;
  const int m = (w << 4) + r;
  const int qo = quad << 3;
  const int mo = m << 2;
  const int col = (blk << 4) + r;
  floatx4 acc = {0.f, 0.f, 0.f, 0.f};
#pragma unroll 4
  for (int kk = 0; kk < HID; kk += 32) {
    short8 ah, al;
    ld_frag(h1slot + (((kk + qo) >> 2) << 8) + mo, ah, al);
    short8 b1 = *(const short8*)(fh + col * HID + kk + qo);
    short8 b2 = *(const short8*)(fl + col * HID + kk + qo);
    acc = mfma3(ah, al, b1, b2, acc);
  }
  float bias = fcb[col];
  const int kb = col >> 2, jj = col & 3;
#pragma unroll
  for (int i = 0; i < 4; ++i) {
    int b = (w << 4) + (quad << 2) + i;
    float v = acc[i] + bias;
    out[(b * FUTL + t) * FIN + col] = v;
    st_sc_u32(dxslot + ((kb << 6) + b) * 4 + jj, packsplit(v));
  }
}

// ---------------- the persistent kernel ----------------
__global__ __launch_bounds__(NTHR, 1) void lstm_coop(Params p) {
  __shared__ u16 wsmem[32768];              // 64 KB: hi at [0], lo at [16K]
  u16* wh = wsmem;
  u16* wl = wsmem + 16 * 1024;
  const int blk = blockIdx.x;
  const int grp = blk >> 7;
  const int lidx = blk & 127;
  const int hc = lidx << 2;
  const int tid = threadIdx.x;

  u32* fcf = FCFLAG(p.cnt);
  u32* L0 = LEAVES0(p.cnt);
  u32* L1 = LEAVES1(p.cnt);
  u32* myLeaf = (grp ? L1 : L0) + ((lidx >> 3) << 4);
  u32* goArr = grp ? GO1(p.cnt) : GO0(p.cnt);
  u32* myGo = goArr + (lidx << 4);

  floatx4 bse, bsd;
  {
    int ch = hc + (tid & 3);
    const float* bi  = grp ? p.beih1 : p.beih0;
    const float* bh2 = grp ? p.behh1 : p.behh0;
    const float* di  = grp ? p.bdih1 : p.bdih0;
    const float* dh2 = grp ? p.bdhh1 : p.bdhh0;
#pragma unroll
    for (int q = 0; q < 4; ++q) {
      bse[q] = bi[q * HID + ch] + bh2[q * HID + ch];
      bsd[q] = di[q * HID + ch] + dh2[q * HID + ch];
    }
  }
  float creg = 0.f;

  if (!grp) {
    // ======== group0: layer 0 (+fc on blocks 0..3 in decoder) ========
    load_w_lds<false>(p.we0h, p.we0l, wh, wl, hc);
    for (int s = 0; s < SEQT; ++s) {
      u32 tok = (u32)(s + 1);
      if (lidx == 0) {
        master_wait(L0, 8u * (u32)s, (s >= 4) ? L1 : nullptr,
                    (s >= 4) ? 8u * (u32)(s - 3) : 0u, nullptr, 0u);
        if (tid < 127) AST(goArr + ((tid + 1) << 4), tok);
      } else {
        worker_wait(myGo, tok);
      }
      fence_acq();
      layer_step<false>(p.xp + (size_t)s * SLOT_XP,
                        p.h0p + ((s + 3) & 3) * SLOT_HP,
                        wh, wl, bse, creg,
                        p.h0p + (s & 3) * SLOT_HP + (lidx << 8));
      arrive(myLeaf);
    }
    load_w_lds<false>(p.wd0h, p.wd0l, wh, wl, hc);
    for (int t = 0; t < FUTL; ++t) {
      u32 tok = (u32)(513 + t);
      if (lidx == 0) {
        master_wait(L0, 8u * (u32)(512 + t), L1, 8u * (u32)(509 + t), fcf, 4u * (u32)t);
        if (tid < 127) AST(goArr + ((tid + 1) << 4), tok);
      } else {
        worker_wait(myGo, tok);
      }
      fence_acq();
      layer_step<false>(p.dxp + (t & 1) * SLOT_XP,
                        p.h0p + ((511 + t) & 3) * SLOT_HP,
                        wh, wl, bsd, creg,
                        p.h0p + ((512 + t) & 3) * SLOT_HP + (lidx << 8));
      arrive(myLeaf);
      if (lidx < 4) {
        master_wait(L1, 8u * (u32)(513 + t), nullptr, 0u, nullptr, 0u);  // h1-dec(t) ready
        fence_acq();
        fc_step(t, lidx, p.h1p + ((512 + t) & 3) * SLOT_HP,
                p.fch, p.fcl, p.fcb, p.out,
                p.dxp + ((t + 1) & 1) * SLOT_XP);
        WAITVM0();
        __syncthreads();
        if (tid == 0) AADD(fcf, 1u);
      }
    }
  } else {
    // ======== group1: layer 1 ========
    load_w_lds<true>(p.we1h, p.we1l, wh, wl, hc);
    for (int t = 0; t < SEQT; ++t) {
      u32 tok = (u32)(t + 1);
      if (lidx == 0) {
        master_wait(L1, 8u * (u32)t, L0, 8u * (u32)(t + 1), nullptr, 0u);
        if (tid < 127) AST(goArr + ((tid + 1) << 4), tok);
      } else {
        worker_wait(myGo, tok);
      }
      fence_acq();
      layer_step<true>(p.h0p + (t & 3) * SLOT_HP,
                       p.h1p + ((t + 3) & 3) * SLOT_HP,
                       wh, wl, bse, creg,
                       p.h1p + (t & 3) * SLOT_HP + (lidx << 8));
      arrive(myLeaf);
    }
    load_w_lds<true>(p.wd1h, p.wd1l, wh, wl, hc);
    for (int t = 0; t < FUTL; ++t) {
      u32 tok = (u32)(513 + t);
      if (lidx == 0) {
        master_wait(L1, 8u * (u32)(512 + t), L0, 8u * (u32)(513 + t),
                    (t >= 4) ? fcf : nullptr, (t >= 4) ? 4u * (u32)(t - 3) : 0u);
        if (tid < 127) AST(goArr + ((tid + 1) << 4), tok);
      } else {
        worker_wait(myGo, tok);
      }
      fence_acq();
      layer_step<true>(p.h0p + ((512 + t) & 3) * SLOT_HP,
                       p.h1p + ((511 + t) & 3) * SLOT_HP,
                       wh, wl, bsd, creg,
                       p.h1p + ((512 + t) & 3) * SLOT_HP + (lidx << 8));
      arrive(myLeaf);
    }
  }
}

// ---------------- launch ----------------
extern "C" void kernel_launch(void* const* d_in, const int* in_sizes, int n_in,
                              void* d_out, int out_size, void* d_ws, size_t ws_size,
                              hipStream_t stream) {
  (void)in_sizes; (void)n_in; (void)out_size; (void)ws_size;
  const float* in_seq = (const float*)d_in[0];
  const float* eWih0 = (const float*)d_in[1];
  const float* eWhh0 = (const float*)d_in[2];
  const float* ebih0 = (const float*)d_in[3];
  const float* ebhh0 = (const float*)d_in[4];
  const float* eWih1 = (const float*)d_in[5];
  const float* eWhh1 = (const float*)d_in[6];
  const float* ebih1 = (const float*)d_in[7];
  const float* ebhh1 = (const float*)d_in[8];
  const float* dWih0 = (const float*)d_in[9];
  const float* dWhh0 = (const float*)d_in[10];
  const float* dbih0 = (const float*)d_in[11];
  const float* dbhh0 = (const float*)d_in[12];
  const float* dWih1 = (const float*)d_in[13];
  const float* dWhh1 = (const float*)d_in[14];
  const float* dbih1 = (const float*)d_in[15];
  const float* dbhh1 = (const float*)d_in[16];
  const float* fcW  = (const float*)d_in[17];
  const float* fcb  = (const float*)d_in[18];

  char* ws = (char*)d_ws;
  u16* we0h = (u16*)(ws + OFF_WHI_E0); u16* we0l = (u16*)(ws + OFF_WLO_E0);
  u16* we1h = (u16*)(ws + OFF_WHI_E1); u16* we1l = (u16*)(ws + OFF_WLO_E1);
  u16* wd0h = (u16*)(ws + OFF_WHI_D0); u16* wd0l = (u16*)(ws + OFF_WLO_D0);
  u16* wd1h = (u16*)(ws + OFF_WHI_D1); u16* wd1l = (u16*)(ws + OFF_WLO_D1);
  u16* fch  = (u16*)(ws + OFF_FCHI);   u16* fcl  = (u16*)(ws + OFF_FCLO);
  u32* xp   = (u32*)(ws + OFF_XP);
  u32* h0p  = (u32*)(ws + OFF_H0P);
  u32* h1p  = (u32*)(ws + OFF_H1P);
  u32* dxp  = (u32*)(ws + OFF_DXP);
  u32* cnt  = (u32*)(ws + OFF_CNT);

  // zero rings + counters (ws is poisoned 0xAA before every call)
  hipMemsetAsync(ws + OFF_H0P, 0, MEMSET_BYTES, stream);

  k_split_pair<<<512, 256, 0, stream>>>(eWih0, eWhh0, FIN, K0, we0h, we0l);
  k_split_pair<<<512, 256, 0, stream>>>(eWih1, eWhh1, HID, K1, we1h, we1l);
  k_split_pair<<<512, 256, 0, stream>>>(dWih0, dWhh0, FIN, K0, wd0h, wd0l);
  k_split_pair<<<512, 256, 0, stream>>>(dWih1, dWhh1, HID, K1, wd1h, wd1l);
  k_split_flat<<<128, 256, 0, stream>>>(fcW, fch, fcl, FIN * HID);
  k_pack_x<<<1024, 256, 0, stream>>>(in_seq, xp, dxp);

  Params p;
  p.we0h = we0h; p.we0l = we0l; p.we1h = we1h; p.we1l = we1l;
  p.wd0h = wd0h; p.wd0l = wd0l; p.wd1h = wd1h; p.wd1l = wd1l;
  p.fch = fch; p.fcl = fcl;
  p.xp = xp; p.h0p = h0p; p.h1p = h1p; p.dxp = dxp;
  p.beih0 = ebih0; p.behh0 = ebhh0; p.beih1 = ebih1; p.behh1 = ebhh1;
  p.bdih0 = dbih0; p.bdhh0 = dbhh0; p.bdih1 = dbih1; p.bdhh1 = dbhh1;
  p.fcb = fcb;
  p.out = (float*)d_out;
  p.cnt = cnt;

  lstm_coop<<<dim3(NBLK), dim3(NTHR), 0, stream>>>(p);
}

// Round 4
// 5997.173 us; speedup vs baseline: 2.7151x; 1.4891x over previous
//
#include <hip/hip_runtime.h>
#include <stdint.h>

typedef __attribute__((ext_vector_type(8))) short short8;
typedef __attribute__((ext_vector_type(4))) float floatx4;
typedef unsigned short u16;
typedef unsigned int u32;

constexpr int BSZ = 64;     // batch
constexpr int SEQT = 512;   // encoder timesteps
constexpr int FIN = 64;     // input features F
constexpr int HID = 512;    // hidden H
constexpr int NG = 2048;    // 4*H gate rows
constexpr int FUTL = 96;    // decoder steps
constexpr int K0 = FIN + HID;   // 576
constexpr int K1 = HID + HID;   // 1024
constexpr int K0P = K0 + 8;     // padded LDS row stride for layer-0 W
constexpr int NBLK = 256;
constexpr int NTHR = 256;

// packed activation slabs: one slab = 4 cols x 64 batch x u32(hi|lo<<16) = 1KB
constexpr int SLOT_HP = 128 * 256;  // u32 per h slot (128 slabs)
constexpr int SLOT_XP = 16 * 256;   // u32 per x/dx slot (16 slabs)
constexpr int NSLOT_H = 65;         // slot 0 = zeros; slot(u) = u%64+1
constexpr int NSLOT_DX = FUTL + 1;  // unique slot per decoder step

// ---------------- workspace layout (bytes) ----------------
constexpr size_t S_W0 = (size_t)NG * K0 * 2;
constexpr size_t S_W1 = (size_t)NG * K1 * 2;
constexpr size_t S_FC = (size_t)FIN * HID * 2;

constexpr size_t OFF_WHI_E0 = 0;
constexpr size_t OFF_WLO_E0 = OFF_WHI_E0 + S_W0;
constexpr size_t OFF_WHI_E1 = OFF_WLO_E0 + S_W0;
constexpr size_t OFF_WLO_E1 = OFF_WHI_E1 + S_W1;
constexpr size_t OFF_WHI_D0 = OFF_WLO_E1 + S_W1;
constexpr size_t OFF_WLO_D0 = OFF_WHI_D0 + S_W0;
constexpr size_t OFF_WHI_D1 = OFF_WLO_D0 + S_W0;
constexpr size_t OFF_WLO_D1 = OFF_WHI_D1 + S_W1;
constexpr size_t OFF_FCHI  = OFF_WLO_D1 + S_W1;
constexpr size_t OFF_FCLO  = OFF_FCHI + S_FC;
constexpr size_t OFF_XP    = OFF_FCLO + S_FC;                        // 512 slots
constexpr size_t OFF_H0P   = OFF_XP + (size_t)SEQT * SLOT_XP * 4;
constexpr size_t OFF_H1P   = OFF_H0P + (size_t)NSLOT_H * SLOT_HP * 4;
constexpr size_t OFF_DXP   = OFF_H1P + (size_t)NSLOT_H * SLOT_HP * 4;
constexpr size_t OFF_CNT   = OFF_DXP + (size_t)NSLOT_DX * SLOT_XP * 4;
constexpr size_t CNT_BYTES = 65536;

// cnt layout (u32 idx): fcdone @0 (4 cells x16); done0 @256 (128x16); done1 @2304;
// go0 @4352; go1 @6400.
#define FCF(c)   ((c) + 0)
#define DONE0(c) ((c) + 256)
#define DONE1(c) ((c) + 2304)
#define GO0(c)   ((c) + 4352)
#define GO1(c)   ((c) + 6400)

// ---------------- bf16 helpers ----------------
__device__ __forceinline__ u16 f2bf(float f) {
  u32 u = __float_as_uint(f);
  u += 0x7FFFu + ((u >> 16) & 1u);   // RNE
  return (u16)(u >> 16);
}
__device__ __forceinline__ float bf2f(u16 h) { return __uint_as_float(((u32)h) << 16); }
__device__ __forceinline__ u32 packsplit(float v) {
  u16 h = f2bf(v);
  u16 l = f2bf(v - bf2f(h));
  return (u32)h | ((u32)l << 16);
}

__device__ __forceinline__ float sigf(float x) { return 1.f / (1.f + __expf(-x)); }
__device__ __forceinline__ float tanh_f(float x) {
  float xx = fminf(20.f, fmaxf(-20.f, x));
  float e = __expf(-2.f * xx);
  return (1.f - e) / (1.f + e);
}

__device__ __forceinline__ floatx4 mfma3(short8 ah, short8 al, short8 bh, short8 bl, floatx4 acc) {
  acc = __builtin_amdgcn_mfma_f32_16x16x32_bf16(ah, bh, acc, 0, 0, 0);
  acc = __builtin_amdgcn_mfma_f32_16x16x32_bf16(ah, bl, acc, 0, 0, 0);
  acc = __builtin_amdgcn_mfma_f32_16x16x32_bf16(al, bh, acc, 0, 0, 0);
  return acc;
}

// write-through store: lands at the coherent point (IF$); no release fence needed.
__device__ __forceinline__ void st_sc_u32(u32* p, u32 v) {
  asm volatile("global_store_dword %0, %1, off sc0 sc1" :: "v"(p), "v"(v) : "memory");
}
#define WAITVM0() asm volatile("s_waitcnt vmcnt(0)" ::: "memory")

#define ALD(p) __hip_atomic_load((p), __ATOMIC_RELAXED, __HIP_MEMORY_SCOPE_AGENT)
#define AST(p, v) __hip_atomic_store((p), (v), __ATOMIC_RELAXED, __HIP_MEMORY_SCOPE_AGENT)

__device__ __forceinline__ int slotof(int u) { return u < 0 ? 0 : ((u & 63) + 1); }

// packed A-fragment load: 8 cols (2 slabs) for batch row m -> hi/lo short8 (cached loads)
__device__ __forceinline__ void ld_frag(const u32* p, short8& ah, short8& al) {
  uint4 a = *(const uint4*)p;
  uint4 b = *(const uint4*)(p + 256);
  union { u32 u[4]; short8 s; } H, L;
  H.u[0] = __builtin_amdgcn_perm(a.y, a.x, 0x05040100u);
  L.u[0] = __builtin_amdgcn_perm(a.y, a.x, 0x07060302u);
  H.u[1] = __builtin_amdgcn_perm(a.w, a.z, 0x05040100u);
  L.u[1] = __builtin_amdgcn_perm(a.w, a.z, 0x07060302u);
  H.u[2] = __builtin_amdgcn_perm(b.y, b.x, 0x05040100u);
  L.u[2] = __builtin_amdgcn_perm(b.y, b.x, 0x07060302u);
  H.u[3] = __builtin_amdgcn_perm(b.w, b.z, 0x05040100u);
  L.u[3] = __builtin_amdgcn_perm(b.w, b.z, 0x07060302u);
  ah = H.s; al = L.s;
}

// ---------------- prep kernels ----------------
__global__ void k_split_pair(const float* __restrict__ Wih, const float* __restrict__ Whh,
                             int ins, int K, u16* __restrict__ hi, u16* __restrict__ lo) {
  int n = NG * K;
  for (int idx = blockIdx.x * blockDim.x + threadIdx.x; idx < n; idx += gridDim.x * blockDim.x) {
    int row = idx / K;
    int k = idx - row * K;
    float v = (k < ins) ? Wih[row * ins + k] : Whh[row * HID + (k - ins)];
    u16 h = f2bf(v);
    hi[idx] = h;
    lo[idx] = f2bf(v - bf2f(h));
  }
}

__global__ void k_split_flat(const float* __restrict__ src, u16* __restrict__ hi,
                             u16* __restrict__ lo, int n) {
  for (int idx = blockIdx.x * blockDim.x + threadIdx.x; idx < n; idx += gridDim.x * blockDim.x) {
    float v = src[idx];
    u16 h = f2bf(v);
    hi[idx] = h;
    lo[idx] = f2bf(v - bf2f(h));
  }
}

// input_seq [B][T][F] -> packed slabs xp[t][kb][m][j]; also dxp slot 0 from t=T-1
__global__ void k_pack_x(const float* __restrict__ x, u32* __restrict__ xp, u32* __restrict__ dxp) {
  int n = BSZ * SEQT * FIN;
  for (int idx = blockIdx.x * blockDim.x + threadIdx.x; idx < n; idx += gridDim.x * blockDim.x) {
    int t = idx / (BSZ * FIN);
    int rem = idx - t * (BSZ * FIN);
    int b = rem >> 6;
    int f = rem & 63;
    u32 pk = packsplit(x[(b * SEQT + t) * FIN + f]);
    int off = ((f >> 2) * 64 + b) * 4 + (f & 3);
    xp[t * SLOT_XP + off] = pk;
    if (t == SEQT - 1) dxp[off] = pk;
  }
}

// ---------------- params ----------------
struct Params {
  const u16 *we0h, *we0l, *we1h, *we1l;
  const u16 *wd0h, *wd0l, *wd1h, *wd1l;
  const u16 *fch, *fcl;
  const u32 *xp;
  u32 *h0p, *h1p, *dxp;
  const float *beih0, *behh0, *beih1, *behh1;
  const float *bdih0, *bdhh0, *bdih1, *bdhh1;
  const float *fcb;
  float *out;
  u32 *cnt;
};

// ---------------- sync ----------------
// Master sweep: wave0 checks 128 own cells (2/lane) + optional 128 foreign + 4 fc cells.
__device__ void master_wait(u32* own, u32 ownT, u32* fore, u32 foreT, u32* fcf, u32 fcT) {
  if (threadIdx.x < 64) {
    int l = threadIdx.x;
    for (;;) {
      bool ok = ALD(own + l * 16) >= ownT && ALD(own + (l + 64) * 16) >= ownT;
      if (fore) ok = ok && ALD(fore + l * 16) >= foreT && ALD(fore + (l + 64) * 16) >= foreT;
      if (fcf && l < 4) ok = ok && ALD(fcf + l * 16) >= fcT;
      if (__all(ok)) break;
      __builtin_amdgcn_s_sleep(2);
    }
  }
  __syncthreads();
}

// fc-block sweep of a 128-cell done array
__device__ void sweep128(u32* arr, u32 T) {
  if (threadIdx.x < 64) {
    int l = threadIdx.x;
    while (!__all(ALD(arr + l * 16) >= T && ALD(arr + (l + 64) * 16) >= T))
      __builtin_amdgcn_s_sleep(2);
  }
  __syncthreads();
}

// Worker: poll OWN go cell only (1 poller per line).
__device__ __forceinline__ void worker_wait(u32* cell, u32 tok) {
  if (threadIdx.x == 0) {
    while (ALD(cell) < tok) __builtin_amdgcn_s_sleep(2);
  }
  __syncthreads();
}

__device__ __forceinline__ void fence_acq() {
  __builtin_amdgcn_fence(__ATOMIC_ACQUIRE, "agent");   // buffer_inv: epoch boundary only
}

// Arrival: drain own sc stores (each wave), then one token store to this block's cell.
__device__ __forceinline__ void arrive(u32* cell, u32 tok) {
  WAITVM0();
  __syncthreads();
  if (threadIdx.x == 0) AST(cell, tok);
}

// ---------------- W -> LDS (persistent) ----------------
template <bool IS_L1>
__device__ void load_w_lds(const u16* __restrict__ gh, const u16* __restrict__ gl,
                           u16* wh, u16* wl, int hc) {
  constexpr int K = IS_L1 ? K1 : K0;
  for (int i = threadIdx.x; i < 16 * K; i += NTHR) {
    int rr, k;
    if (IS_L1) { rr = i >> 10; k = i & 1023; }
    else       { rr = i / K0;  k = i - rr * K0; }
    int gc = ((rr >> 2) * HID) + hc + (rr & 3);   // row r -> gate q=r>>2, col j=r&3
    int dst = IS_L1 ? ((rr << 10) + ((((k >> 3) ^ rr)) << 3) + (k & 7))
                    : (rr * K0P + k);
    wh[dst] = gh[(size_t)gc * K + k];
    wl[dst] = gl[(size_t)gc * K + k];
  }
  __syncthreads();
}

// ---------------- one LSTM layer step (block's 4 h-cols) ----------------
template <bool IS_L1>
__device__ void layer_step(const u32* __restrict__ s0p, const u32* __restrict__ s1p,
                           const u16* __restrict__ wh, const u16* __restrict__ wl,
                           floatx4 bs, float& creg, u32* __restrict__ oslab) {
  constexpr int LEN0 = IS_L1 ? HID : FIN;
  const int tid = threadIdx.x, lane = tid & 63, w = tid >> 6;
  const int quad = lane >> 4, r = lane & 15;
  const int m = (w << 4) + r;
  const int qo = quad << 3;
  const int mo = m << 2;
  floatx4 acc = {0.f, 0.f, 0.f, 0.f};

#pragma unroll 2
  for (int kk = 0; kk < LEN0; kk += 32) {
    short8 ah, al;
    ld_frag(s0p + (((kk + qo) >> 2) << 8) + mo, ah, al);
    int woff;
    if (IS_L1) { int c = (kk >> 3) + quad; woff = (r << 10) + ((c ^ r) << 3); }
    else       { woff = r * K0P + kk + qo; }
    short8 bh = *(const short8*)(wh + woff);
    short8 bl = *(const short8*)(wl + woff);
    acc = mfma3(ah, al, bh, bl, acc);
  }
#pragma unroll 4
  for (int kk = 0; kk < HID; kk += 32) {
    short8 ah, al;
    ld_frag(s1p + (((kk + qo) >> 2) << 8) + mo, ah, al);
    const int kg = kk + LEN0;
    int woff;
    if (IS_L1) { int c = (kg >> 3) + quad; woff = (r << 10) + ((c ^ r) << 3); }
    else       { woff = r * K0P + kg + qo; }
    short8 bh = *(const short8*)(wh + woff);
    short8 bl = *(const short8*)(wl + woff);
    acc = mfma3(ah, al, bh, bl, acc);
  }

  // Epilogue: C[row=quad*4+i][col=r]; redistribute so each thread owns one (b, j).
  const int j = lane & 3;
  const int rw = lane >> 2;
  const int isel = rw & 3;
  const int slb = lane & 48;
  float gate[4];
#pragma unroll
  for (int q = 0; q < 4; ++q) {
    const int sl = slb + (q << 2) + j;
    float t0 = __shfl(acc[0], sl, 64);
    float t1 = __shfl(acc[1], sl, 64);
    float t2 = __shfl(acc[2], sl, 64);
    float t3 = __shfl(acc[3], sl, 64);
    gate[q] = (isel == 0) ? t0 : (isel == 1) ? t1 : (isel == 2) ? t2 : t3;
  }

  float iv = gate[0] + bs[0];
  float fv = gate[1] + bs[1];
  float gv = gate[2] + bs[2];
  float ov = gate[3] + bs[3];
  float cn = fmaf(sigf(fv), creg, sigf(iv) * tanh_f(gv));
  float hn = sigf(ov) * tanh_f(cn);
  creg = cn;
  st_sc_u32(oslab + tid, packsplit(hn));   // wave-contiguous 256B write-through
}

// ---------------- decoder fc (g0 blocks 0..3): out = dh1 @ fcW^T + fcb ----------------
__device__ void fc_step(int t, int blk, const u32* __restrict__ h1slot,
                        const u16* __restrict__ fh, const u16* __restrict__ fl,
                        const float* __restrict__ fcb, float* __restrict__ out,
                        u32* __restrict__ dxslot) {
  const int tid = threadIdx.x, lane = tid & 63, w = tid >> 6;
  const int quad = lane >> 4, r = lane & 15;
  const int m = (w << 4) + r;
  const int qo = quad << 3;
  const int mo = m << 2;
  const int col = (blk << 4) + r;
  floatx4 acc = {0.f, 0.f, 0.f, 0.f};
#pragma unroll 4
  for (int kk = 0; kk < HID; kk += 32) {
    short8 ah, al;
    ld_frag(h1slot + (((kk + qo) >> 2) << 8) + mo, ah, al);
    short8 b1 = *(const short8*)(fh + col * HID + kk + qo);
    short8 b2 = *(const short8*)(fl + col * HID + kk + qo);
    acc = mfma3(ah, al, b1, b2, acc);
  }
  float bias = fcb[col];
  const int kb = col >> 2, jj = col & 3;
#pragma unroll
  for (int i = 0; i < 4; ++i) {
    int b = (w << 4) + (quad << 2) + i;
    float v = acc[i] + bias;
    out[(b * FUTL + t) * FIN + col] = v;
    st_sc_u32(dxslot + ((kb << 6) + b) * 4 + jj, packsplit(v));
  }
}

// ---------------- the persistent kernel ----------------
__global__ __launch_bounds__(NTHR, 1) void lstm_coop(Params p) {
  __shared__ u16 wsmem[32768];              // 64 KB: hi at [0], lo at [16K]
  u16* wh = wsmem;
  u16* wl = wsmem + 16 * 1024;
  const int blk = blockIdx.x;
  const int grp = blk >> 7;
  const int lidx = blk & 127;
  const int hc = lidx << 2;
  const int tid = threadIdx.x;

  u32* fcf = FCF(p.cnt);
  u32* d0 = DONE0(p.cnt);
  u32* d1 = DONE1(p.cnt);
  u32* goArr = grp ? GO1(p.cnt) : GO0(p.cnt);
  u32* myGo = goArr + lidx * 16;
  u32* myDone = (grp ? d1 : d0) + lidx * 16;

  floatx4 bse, bsd;
  {
    int ch = hc + (tid & 3);
    const float* bi  = grp ? p.beih1 : p.beih0;
    const float* bh2 = grp ? p.behh1 : p.behh0;
    const float* di  = grp ? p.bdih1 : p.bdih0;
    const float* dh2 = grp ? p.bdhh1 : p.bdhh0;
#pragma unroll
    for (int q = 0; q < 4; ++q) {
      bse[q] = bi[q * HID + ch] + bh2[q * HID + ch];
      bsd[q] = di[q * HID + ch] + dh2[q * HID + ch];
    }
  }
  float creg = 0.f;

  if (!grp) {
    // ======== group0: layer 0 (+fc on blocks 0..3 in decoder) ========
    load_w_lds<false>(p.we0h, p.we0l, wh, wl, hc);
    for (int s = 0; s < SEQT; ++s) {
      u32 tok = (u32)(s + 1);
      if (lidx == 0) {
        // far-lag gate on done1 (never binds in steady state; protects slot reuse)
        master_wait(d0, (u32)s, (s >= 63) ? d1 : nullptr, (u32)(s - 63), nullptr, 0u);
        if (tid < 127) AST(goArr + ((tid + 1) << 4), tok);
      } else {
        worker_wait(myGo, tok);
      }
      if ((s & 63) == 0 && s) fence_acq();   // epoch boundary: clear recycled-slot lines
      layer_step<false>(p.xp + (size_t)s * SLOT_XP,
                        p.h0p + (size_t)slotof(s - 1) * SLOT_HP,
                        wh, wl, bse, creg,
                        p.h0p + (size_t)slotof(s) * SLOT_HP + (lidx << 8));
      arrive(myDone, tok);
    }
    load_w_lds<false>(p.wd0h, p.wd0l, wh, wl, hc);
    for (int t = 0; t < FUTL; ++t) {
      u32 tok = (u32)(513 + t);
      if (lidx == 0) {
        master_wait(d0, (u32)(512 + t), d1, (u32)(449 + t), fcf, (u32)t);
        if (tid < 127) AST(goArr + ((tid + 1) << 4), tok);
      } else {
        worker_wait(myGo, tok);
      }
      if ((t & 63) == 0) fence_acq();        // u=512, 576 epoch boundaries
      layer_step<false>(p.dxp + (size_t)t * SLOT_XP,
                        p.h0p + (size_t)slotof(511 + t) * SLOT_HP,
                        wh, wl, bsd, creg,
                        p.h0p + (size_t)slotof(512 + t) * SLOT_HP + (lidx << 8));
      arrive(myDone, tok);
      if (lidx < 4) {
        sweep128(d1, (u32)(513 + t));        // h1-dec(t) ready
        fc_step(t, lidx, p.h1p + (size_t)slotof(512 + t) * SLOT_HP,
                p.fch, p.fcl, p.fcb, p.out,
                p.dxp + (size_t)(t + 1) * SLOT_XP);
        WAITVM0();
        __syncthreads();
        if (tid == 0) AST(fcf + lidx * 16, (u32)(t + 1));
      }
    }
  } else {
    // ======== group1: layer 1 ========
    load_w_lds<true>(p.we1h, p.we1l, wh, wl, hc);
    for (int t = 0; t < SEQT; ++t) {
      u32 tok = (u32)(t + 1);
      if (lidx == 0) {
        master_wait(d1, (u32)t, d0, (u32)(t + 1), nullptr, 0u);
        if (tid < 127) AST(goArr + ((tid + 1) << 4), tok);
      } else {
        worker_wait(myGo, tok);
      }
      if ((t & 63) == 0 && t) fence_acq();
      layer_step<true>(p.h0p + (size_t)slotof(t) * SLOT_HP,
                       p.h1p + (size_t)slotof(t - 1) * SLOT_HP,
                       wh, wl, bse, creg,
                       p.h1p + (size_t)slotof(t) * SLOT_HP + (lidx << 8));
      arrive(myDone, tok);
    }
    load_w_lds<true>(p.wd1h, p.wd1l, wh, wl, hc);
    for (int t = 0; t < FUTL; ++t) {
      u32 tok = (u32)(513 + t);
      if (lidx == 0) {
        master_wait(d1, (u32)(512 + t), d0, (u32)(513 + t),
                    (t >= 64) ? fcf : nullptr, (u32)(t - 63));
        if (tid < 127) AST(goArr + ((tid + 1) << 4), tok);
      } else {
        worker_wait(myGo, tok);
      }
      if ((t & 63) == 0) fence_acq();
      layer_step<true>(p.h0p + (size_t)slotof(512 + t) * SLOT_HP,
                       p.h1p + (size_t)slotof(511 + t) * SLOT_HP,
                       wh, wl, bsd, creg,
                       p.h1p + (size_t)slotof(512 + t) * SLOT_HP + (lidx << 8));
      arrive(myDone, tok);
    }
  }
}

// ---------------- launch ----------------
extern "C" void kernel_launch(void* const* d_in, const int* in_sizes, int n_in,
                              void* d_out, int out_size, void* d_ws, size_t ws_size,
                              hipStream_t stream) {
  (void)in_sizes; (void)n_in; (void)out_size; (void)ws_size;
  const float* in_seq = (const float*)d_in[0];
  const float* eWih0 = (const float*)d_in[1];
  const float* eWhh0 = (const float*)d_in[2];
  const float* ebih0 = (const float*)d_in[3];
  const float* ebhh0 = (const float*)d_in[4];
  const float* eWih1 = (const float*)d_in[5];
  const float* eWhh1 = (const float*)d_in[6];
  const float* ebih1 = (const float*)d_in[7];
  const float* ebhh1 = (const float*)d_in[8];
  const float* dWih0 = (const float*)d_in[9];
  const float* dWhh0 = (const float*)d_in[10];
  const float* dbih0 = (const float*)d_in[11];
  const float* dbhh0 = (const float*)d_in[12];
  const float* dWih1 = (const float*)d_in[13];
  const float* dWhh1 = (const float*)d_in[14];
  const float* dbih1 = (const float*)d_in[15];
  const float* dbhh1 = (const float*)d_in[16];
  const float* fcW  = (const float*)d_in[17];
  const float* fcb  = (const float*)d_in[18];

  char* ws = (char*)d_ws;
  u16* we0h = (u16*)(ws + OFF_WHI_E0); u16* we0l = (u16*)(ws + OFF_WLO_E0);
  u16* we1h = (u16*)(ws + OFF_WHI_E1); u16* we1l = (u16*)(ws + OFF_WLO_E1);
  u16* wd0h = (u16*)(ws + OFF_WHI_D0); u16* wd0l = (u16*)(ws + OFF_WLO_D0);
  u16* wd1h = (u16*)(ws + OFF_WHI_D1); u16* wd1l = (u16*)(ws + OFF_WLO_D1);
  u16* fch  = (u16*)(ws + OFF_FCHI);   u16* fcl  = (u16*)(ws + OFF_FCLO);
  u32* xp   = (u32*)(ws + OFF_XP);
  u32* h0p  = (u32*)(ws + OFF_H0P);
  u32* h1p  = (u32*)(ws + OFF_H1P);
  u32* dxp  = (u32*)(ws + OFF_DXP);
  u32* cnt  = (u32*)(ws + OFF_CNT);

  // zero: h0/h1 slot 0 (initial state) + counter region (ws poisoned 0xAA each call)
  hipMemsetAsync(ws + OFF_H0P, 0, (size_t)SLOT_HP * 4, stream);
  hipMemsetAsync(ws + OFF_H1P, 0, (size_t)SLOT_HP * 4, stream);
  hipMemsetAsync(ws + OFF_CNT, 0, CNT_BYTES, stream);

  k_split_pair<<<512, 256, 0, stream>>>(eWih0, eWhh0, FIN, K0, we0h, we0l);
  k_split_pair<<<512, 256, 0, stream>>>(eWih1, eWhh1, HID, K1, we1h, we1l);
  k_split_pair<<<512, 256, 0, stream>>>(dWih0, dWhh0, FIN, K0, wd0h, wd0l);
  k_split_pair<<<512, 256, 0, stream>>>(dWih1, dWhh1, HID, K1, wd1h, wd1l);
  k_split_flat<<<128, 256, 0, stream>>>(fcW, fch, fcl, FIN * HID);
  k_pack_x<<<1024, 256, 0, stream>>>(in_seq, xp, dxp);

  Params p;
  p.we0h = we0h; p.we0l = we0l; p.we1h = we1h; p.we1l = we1l;
  p.wd0h = wd0h; p.wd0l = wd0l; p.wd1h = wd1h; p.wd1l = wd1l;
  p.fch = fch; p.fcl = fcl;
  p.xp = xp; p.h0p = h0p; p.h1p = h1p; p.dxp = dxp;
  p.beih0 = ebih0; p.behh0 = ebhh0; p.beih1 = ebih1; p.behh1 = ebhh1;
  p.bdih0 = dbih0; p.bdhh0 = dbhh0; p.bdih1 = dbih1; p.bdhh1 = dbhh1;
  p.fcb = fcb;
  p.out = (float*)d_out;
  p.cnt = cnt;

  lstm_coop<<<dim3(NBLK), dim3(NTHR), 0, stream>>>(p);
}